// Round 2
// baseline (289.214 us; speedup 1.0000x reference)
//
#include <hip/hip_runtime.h>
#include <math.h>

// EMA along T: y[0]=x[0]; y[t] = (1-a)*y[t-1] + a*x[t], a=0.01.
// 3-kernel reduce-then-scan:
//   1) ends:  per-chunk zero-init local scan -> chunk end states   [B,K,C]
//   2) carry: serial prefix over the K chunk-ends (4 MB, L2-bound)
//   3) scan:  per-chunk scan seeded with carry[k-1], writes out
// K=256 chunks of 32 -> 2048 blocks (8 blocks/CU) for latency hiding.

namespace {
constexpr int B = 8;
constexpr int T = 8192;
constexpr int C = 512;
constexpr float ALPHA = 0.01f;
constexpr float DECAY = 1.0f - ALPHA;   // 0.99
constexpr int CHUNK = 32;               // timesteps per block
constexpr int K = T / CHUNK;            // 256 chunks
constexpr int STRIDE4 = C / 4;          // float4 stride per timestep = 128
constexpr int TPB = C / 4;              // 128 threads, 4 channels each
}

__global__ __launch_bounds__(TPB) void ema_ends_kernel(const float* __restrict__ x,
                                                       float* __restrict__ ends) {
    const int k = blockIdx.x;
    const int b = blockIdx.y;
    const int tid = threadIdx.x;
    const float4* xp = reinterpret_cast<const float4*>(x) +
                       (size_t)(b * T + k * CHUNK) * STRIDE4 + tid;
    float4 y;
    if (k == 0) {
        // y_pre = x[0]: uniform recurrence then yields y[0] = 0.99*x0 + 0.01*x0 = x0
        y = xp[0];
    } else {
        y = make_float4(0.f, 0.f, 0.f, 0.f);
    }
#pragma unroll 8
    for (int t = 0; t < CHUNK; ++t) {
        float4 v = xp[(size_t)t * STRIDE4];
        y.x = DECAY * y.x + ALPHA * v.x;
        y.y = DECAY * y.y + ALPHA * v.y;
        y.z = DECAY * y.z + ALPHA * v.z;
        y.w = DECAY * y.w + ALPHA * v.w;
    }
    reinterpret_cast<float4*>(ends)[(size_t)(b * K + k) * STRIDE4 + tid] = y;
}

// In-place prefix over chunk index k: Y_k = a^CHUNK * Y_{k-1} + end_k.
// Grid: (B) blocks x 128 threads; 512 KB per block, L2-resident.
__global__ __launch_bounds__(TPB) void ema_carry_kernel(float* __restrict__ ends,
                                                        float decay_chunk) {
    const int b = blockIdx.x;
    const int tid = threadIdx.x;
    float4* ep = reinterpret_cast<float4*>(ends) + (size_t)b * K * STRIDE4 + tid;
    float4 y = ep[0];
#pragma unroll 4
    for (int m = 1; m < K; ++m) {
        float4 e = ep[(size_t)m * STRIDE4];
        y.x = decay_chunk * y.x + e.x;
        y.y = decay_chunk * y.y + e.y;
        y.z = decay_chunk * y.z + e.z;
        y.w = decay_chunk * y.w + e.w;
        ep[(size_t)m * STRIDE4] = y;
    }
}

__global__ __launch_bounds__(TPB) void ema_scan_kernel(const float* __restrict__ x,
                                                       const float* __restrict__ ends,
                                                       float* __restrict__ out) {
    const int k = blockIdx.x;
    const int b = blockIdx.y;
    const int tid = threadIdx.x;
    const size_t base4 = (size_t)(b * T + k * CHUNK) * STRIDE4 + tid;
    const float4* xp = reinterpret_cast<const float4*>(x) + base4;
    float4* op = reinterpret_cast<float4*>(out) + base4;

    float4 y;
    if (k == 0) {
        y = xp[0];  // y_pre = x[0] trick
    } else {
        // carry = prefix state of chunk k-1 (single L2-resident float4 load)
        y = reinterpret_cast<const float4*>(ends)[(size_t)(b * K + (k - 1)) * STRIDE4 + tid];
    }
#pragma unroll 8
    for (int t = 0; t < CHUNK; ++t) {
        float4 v = xp[(size_t)t * STRIDE4];
        y.x = DECAY * y.x + ALPHA * v.x;
        y.y = DECAY * y.y + ALPHA * v.y;
        y.z = DECAY * y.z + ALPHA * v.z;
        y.w = DECAY * y.w + ALPHA * v.w;
        op[(size_t)t * STRIDE4] = y;
    }
}

// Exact but slow fallback if ws is too small (one block per batch).
__global__ __launch_bounds__(TPB) void ema_seq_kernel(const float* __restrict__ x,
                                                      float* __restrict__ out) {
    const int b = blockIdx.x;
    const int tid = threadIdx.x;
    const float4* xp = reinterpret_cast<const float4*>(x) + (size_t)b * T * STRIDE4 + tid;
    float4* op = reinterpret_cast<float4*>(out) + (size_t)b * T * STRIDE4 + tid;
    float4 y = xp[0];
    for (int t = 0; t < T; ++t) {
        float4 v = xp[(size_t)t * STRIDE4];
        y.x = DECAY * y.x + ALPHA * v.x;
        y.y = DECAY * y.y + ALPHA * v.y;
        y.z = DECAY * y.z + ALPHA * v.z;
        y.w = DECAY * y.w + ALPHA * v.w;
        op[(size_t)t * STRIDE4] = y;
    }
}

extern "C" void kernel_launch(void* const* d_in, const int* in_sizes, int n_in,
                              void* d_out, int out_size, void* d_ws, size_t ws_size,
                              hipStream_t stream) {
    (void)in_sizes; (void)n_in; (void)out_size;
    const float* x = reinterpret_cast<const float*>(d_in[0]);
    float* out = reinterpret_cast<float*>(d_out);

    const size_t ws_need = (size_t)B * K * C * sizeof(float);  // 4 MB
    const float decay_chunk = (float)pow((double)DECAY, (double)CHUNK);

    if (ws_size >= ws_need) {
        float* ends = reinterpret_cast<float*>(d_ws);
        ema_ends_kernel<<<dim3(K, B), dim3(TPB), 0, stream>>>(x, ends);
        ema_carry_kernel<<<dim3(B), dim3(TPB), 0, stream>>>(ends, decay_chunk);
        ema_scan_kernel<<<dim3(K, B), dim3(TPB), 0, stream>>>(x, ends, out);
    } else {
        ema_seq_kernel<<<dim3(B), dim3(TPB), 0, stream>>>(x, out);
    }
}

// Round 3
// 268.918 us; speedup vs baseline: 1.0755x; 1.0755x over previous
//
#include <hip/hip_runtime.h>
#include <math.h>

// EMA along T: y[0]=x[0]; y[t] = (1-a)*y[t-1] + a*x[t], a=0.01.
// 3-kernel reduce-then-scan:
//   1) ends:  per-chunk zero-init local scan -> chunk end states   [B,K,C]
//   2) carry: serial prefix over K chunk-ends, 16-wide load prefetch for MLP
//   3) scan:  per-chunk scan seeded with ends[k-1] (inclusive), writes out
// K=256 chunks of 32 -> 2048 blocks for ends/scan.

namespace {
constexpr int B = 8;
constexpr int T = 8192;
constexpr int C = 512;
constexpr float ALPHA = 0.01f;
constexpr float DECAY = 1.0f - ALPHA;   // 0.99
constexpr int CHUNK = 32;               // timesteps per block
constexpr int K = T / CHUNK;            // 256 chunks
constexpr int STRIDE4 = C / 4;          // float4 stride per timestep = 128
constexpr int TPB = C / 4;              // 128 threads, 4 channels each
constexpr int CTILE = 16;               // carry prefetch width (MLP)
}

__global__ __launch_bounds__(TPB) void ema_ends_kernel(const float* __restrict__ x,
                                                       float* __restrict__ ends) {
    const int k = blockIdx.x;
    const int b = blockIdx.y;
    const int tid = threadIdx.x;
    const float4* xp = reinterpret_cast<const float4*>(x) +
                       (size_t)(b * T + k * CHUNK) * STRIDE4 + tid;
    float4 y;
    if (k == 0) {
        // y_pre = x[0]: uniform recurrence then yields y[0] = 0.99*x0 + 0.01*x0 = x0
        y = xp[0];
    } else {
        y = make_float4(0.f, 0.f, 0.f, 0.f);
    }
#pragma unroll 8
    for (int t = 0; t < CHUNK; ++t) {
        float4 v = xp[(size_t)t * STRIDE4];
        y.x = DECAY * y.x + ALPHA * v.x;
        y.y = DECAY * y.y + ALPHA * v.y;
        y.z = DECAY * y.z + ALPHA * v.z;
        y.w = DECAY * y.w + ALPHA * v.w;
    }
    reinterpret_cast<float4*>(ends)[(size_t)(b * K + k) * STRIDE4 + tid] = y;
}

// In-place prefix over chunk index k: Y_k = a^CHUNK * Y_{k-1} + end_k.
// Loads are address-independent (only the FMA fold is serial), so prefetch
// CTILE=16 tiles explicitly to keep 16 loads in flight (~500 cyc LLC misses).
__global__ __launch_bounds__(TPB) void ema_carry_kernel(float* __restrict__ ends,
                                                        float decay_chunk) {
    const int b = blockIdx.x;
    const int tid = threadIdx.x;
    float4* ep = reinterpret_cast<float4*>(ends) + (size_t)b * K * STRIDE4 + tid;
    float4 y = make_float4(0.f, 0.f, 0.f, 0.f);
    static_assert(K % CTILE == 0, "");
    for (int base = 0; base < K; base += CTILE) {
        float4 e[CTILE];
#pragma unroll
        for (int i = 0; i < CTILE; ++i)
            e[i] = ep[(size_t)(base + i) * STRIDE4];
#pragma unroll
        for (int i = 0; i < CTILE; ++i) {
            y.x = decay_chunk * y.x + e[i].x;
            y.y = decay_chunk * y.y + e[i].y;
            y.z = decay_chunk * y.z + e[i].z;
            y.w = decay_chunk * y.w + e[i].w;
            ep[(size_t)(base + i) * STRIDE4] = y;
        }
    }
}

__global__ __launch_bounds__(TPB) void ema_scan_kernel(const float* __restrict__ x,
                                                       const float* __restrict__ ends,
                                                       float* __restrict__ out) {
    const int k = blockIdx.x;
    const int b = blockIdx.y;
    const int tid = threadIdx.x;
    const size_t base4 = (size_t)(b * T + k * CHUNK) * STRIDE4 + tid;
    const float4* xp = reinterpret_cast<const float4*>(x) + base4;
    float4* op = reinterpret_cast<float4*>(out) + base4;

    float4 y;
    if (k == 0) {
        y = xp[0];  // y_pre = x[0] trick
    } else {
        // carry = inclusive prefix state of chunk k-1 (single L2/LLC load)
        y = reinterpret_cast<const float4*>(ends)[(size_t)(b * K + (k - 1)) * STRIDE4 + tid];
    }
#pragma unroll 8
    for (int t = 0; t < CHUNK; ++t) {
        float4 v = xp[(size_t)t * STRIDE4];
        y.x = DECAY * y.x + ALPHA * v.x;
        y.y = DECAY * y.y + ALPHA * v.y;
        y.z = DECAY * y.z + ALPHA * v.z;
        y.w = DECAY * y.w + ALPHA * v.w;
        op[(size_t)t * STRIDE4] = y;
    }
}

// Exact but slow fallback if ws is too small (one block per batch).
__global__ __launch_bounds__(TPB) void ema_seq_kernel(const float* __restrict__ x,
                                                      float* __restrict__ out) {
    const int b = blockIdx.x;
    const int tid = threadIdx.x;
    const float4* xp = reinterpret_cast<const float4*>(x) + (size_t)b * T * STRIDE4 + tid;
    float4* op = reinterpret_cast<float4*>(out) + (size_t)b * T * STRIDE4 + tid;
    float4 y = xp[0];
    for (int t = 0; t < T; ++t) {
        float4 v = xp[(size_t)t * STRIDE4];
        y.x = DECAY * y.x + ALPHA * v.x;
        y.y = DECAY * y.y + ALPHA * v.y;
        y.z = DECAY * y.z + ALPHA * v.z;
        y.w = DECAY * y.w + ALPHA * v.w;
        op[(size_t)t * STRIDE4] = y;
    }
}

extern "C" void kernel_launch(void* const* d_in, const int* in_sizes, int n_in,
                              void* d_out, int out_size, void* d_ws, size_t ws_size,
                              hipStream_t stream) {
    (void)in_sizes; (void)n_in; (void)out_size;
    const float* x = reinterpret_cast<const float*>(d_in[0]);
    float* out = reinterpret_cast<float*>(d_out);

    const size_t ws_need = (size_t)B * K * C * sizeof(float);  // 4 MB
    const float decay_chunk = (float)pow((double)DECAY, (double)CHUNK);

    if (ws_size >= ws_need) {
        float* ends = reinterpret_cast<float*>(d_ws);
        ema_ends_kernel<<<dim3(K, B), dim3(TPB), 0, stream>>>(x, ends);
        ema_carry_kernel<<<dim3(B), dim3(TPB), 0, stream>>>(ends, decay_chunk);
        ema_scan_kernel<<<dim3(K, B), dim3(TPB), 0, stream>>>(x, ends, out);
    } else {
        ema_seq_kernel<<<dim3(B), dim3(TPB), 0, stream>>>(x, out);
    }
}